// Round 1
// baseline (455.484 us; speedup 1.0000x reference)
//
#include <hip/hip_runtime.h>
#include <math.h>

#define B_ 64
#define S_ 256
#define V_ 2048
#define NS 12
#define ZOFF 0.001f
#define EPSF 1e-8f
#define NCH 32   // v-chunks in latch phase (64 elems each)

// workspace layout (float offsets)
#define WS_NLE2 0
#define WS_NSP2 1
#define WS_E    64
#define WS_DSP  (WS_E + B_*S_)
#define WS_NL2  (WS_DSP + B_*NCH*S_)
#define WS_COEF (WS_NL2 + B_*NCH*S_)
// coef layout: [B][S][13][4] floats; n<12: (A,B,C,P), n==12: (pop,0,0,0)

__device__ __forceinline__ float wave_sum64(float v) {
#pragma unroll
    for (int m = 32; m >= 1; m >>= 1) v += __shfl_xor(v, m);
    return v;
}

// ---------- Phase A0: norms of latch_enable, should_pop ----------
__global__ void k_norms(const float* __restrict__ le, const float* __restrict__ sp,
                        float* __restrict__ ws) {
    __shared__ float red[4][2];
    int tid = threadIdx.x;
    float a = 0.f, b = 0.f;
    for (int i = tid; i < V_; i += 256) {
        float x = le[i]; a += x * x;
        float y = sp[i]; b += y * y;
    }
    a = wave_sum64(a); b = wave_sum64(b);
    int wave = tid >> 6, lane = tid & 63;
    if (lane == 0) { red[wave][0] = a; red[wave][1] = b; }
    __syncthreads();
    if (tid == 0) {
        float s0 = 0.f, s1 = 0.f;
        for (int w = 0; w < 4; w++) { s0 += red[w][0]; s1 += red[w][1]; }
        ws[WS_NLE2] = s0; ws[WS_NSP2] = s1;
    }
}

// ---------- Phase A: e[b][t] = cossim(latch_enable, x[b,t,:]) ----------
__global__ void __launch_bounds__(256) k_e(const float* __restrict__ x,
                                           const float* __restrict__ le,
                                           float* __restrict__ ws) {
    int bt = blockIdx.x;  // b*S + t
    const float4* xb = (const float4*)(x + (size_t)bt * V_);
    const float4* le4 = (const float4*)le;
    int tid = threadIdx.x;
    float dot = 0.f, nx = 0.f;
#pragma unroll
    for (int k = 0; k < 2; k++) {
        int i = tid + k * 256;
        float4 xv = xb[i], lv = le4[i];
        dot += xv.x * lv.x + xv.y * lv.y + xv.z * lv.z + xv.w * lv.w;
        nx  += xv.x * xv.x + xv.y * xv.y + xv.z * xv.z + xv.w * xv.w;
    }
    dot = wave_sum64(dot); nx = wave_sum64(nx);
    __shared__ float red[4][2];
    int wave = tid >> 6, lane = tid & 63;
    if (lane == 0) { red[wave][0] = dot; red[wave][1] = nx; }
    __syncthreads();
    if (tid == 0) {
        float d = red[0][0] + red[1][0] + red[2][0] + red[3][0];
        float n = red[0][1] + red[1][1] + red[2][1] + red[3][1];
        float nle = fmaxf(sqrtf(ws[WS_NLE2]), EPSF);
        float nxv = fmaxf(sqrtf(n), EPSF);
        ws[WS_E + bt] = d / (nle * nxv);
    }
}

// ---------- Phase B: latch scan over t, elementwise in v ----------
// grid (NCH, B), 64 threads. Writes latch_states + per-step partial stats.
__global__ void k_latch(const float* __restrict__ x,
                        const float* __restrict__ latch_init,
                        const float* __restrict__ sp,
                        float* __restrict__ latch_out,
                        float* __restrict__ ws) {
    int c = blockIdx.x, b = blockIdx.y;
    int lane = threadIdx.x;
    int v = c * 64 + lane;

    __shared__ float se[S_];
    for (int t = lane; t < S_; t += 64) se[t] = ws[WS_E + b * S_ + t];
    __syncthreads();

    float latch = latch_init[b * V_ + v];
    float spv = sp[v];
    const float* xb = x + (size_t)b * S_ * V_ + v;
    float* lo = latch_out + (size_t)b * S_ * V_ + v;
    float* dspp = ws + WS_DSP + (size_t)(b * NCH + c) * S_;
    float* nl2p = ws + WS_NL2 + (size_t)(b * NCH + c) * S_;

    // stats slot t holds stats of the latch USED at step t (pre-update)
    {
        float d = wave_sum64(spv * latch);
        float n = wave_sum64(latch * latch);
        if (lane == 0) { dspp[0] = d; nl2p[0] = n; }
    }
    for (int t = 0; t < S_; t++) {
        float xv = xb[(size_t)t * V_];
        float e = se[t];
        latch = fmaf(e, xv - latch, latch);   // (1-e)*latch + e*x
        lo[(size_t)t * V_] = latch;
        if (t < S_ - 1) {
            float d = wave_sum64(spv * latch);
            float n = wave_sum64(latch * latch);
            if (lane == 0) { dspp[t + 1] = d; nl2p[t + 1] = n; }
        }
    }
}

// ---------- Phase C: pointer recurrence -> coefficients ----------
// grid (B), 64 threads. Lane n<12 owns pointer slot n.
__global__ void k_pointer(const float* __restrict__ sharpen_ptr,
                          float* __restrict__ ws,
                          float* __restrict__ pops_out) {
    int b = blockIdx.x, lane = threadIdx.x;
    __shared__ float sdsp[S_], snl2[S_];
    // reduce chunk partials
    for (int t = lane; t < S_; t += 64) {
        const float* dp = ws + WS_DSP + (size_t)b * NCH * S_ + t;
        const float* np = ws + WS_NL2 + (size_t)b * NCH * S_ + t;
        float d = 0.f, n = 0.f;
#pragma unroll
        for (int c = 0; c < NCH; c++) { d += dp[c * S_]; n += np[c * S_]; }
        sdsp[t] = d; snl2[t] = n;
    }
    __syncthreads();

    float sharpen = sharpen_ptr[0];
    float nsp = fmaxf(sqrtf(ws[WS_NSP2]), EPSF);
    float p = (lane == 0) ? 1.f : 0.f;
    const float NEG = -1e30f;
    float* coef = ws + WS_COEF + (size_t)b * S_ * 13 * 4;

    for (int t = 0; t < S_; t++) {
        float cs = sdsp[t] / (nsp * fmaxf(sqrtf(snl2[t]), EPSF));
        float pop = cs > 0.f ? cs : expm1f(cs);
        float push = 1.f - pop;
        // softmax over 12 lanes within the 16-lane group
        float z = (lane < NS) ? p * sharpen : NEG;
        float m = z;
#pragma unroll
        for (int mm = 1; mm < 16; mm <<= 1) m = fmaxf(m, __shfl_xor(m, mm));
        float ez = (lane < NS) ? __expf(z - m) : 0.f;
        float s = ez;
#pragma unroll
        for (int mm = 1; mm < 16; mm <<= 1) s += __shfl_xor(s, mm);
        float psh = ez / s;
        int nm1 = (lane == 0) ? 11 : lane - 1;    // (n-1) mod 12
        int np1 = (lane == 11) ? 0 : lane + 1;    // (n+1) mod 12
        float push_p = __shfl(psh, nm1);
        float pop_p  = __shfl(psh, np1);
        float bb = push * push_p;
        float cc = pop * psh;
        float a  = 1.f - bb - cc;
        float pnew = fmaf(pop, pop_p, bb);
        if (lane < NS) {
            float4* dst = (float4*)(coef + (size_t)(t * 13 + lane) * 4);
            *dst = make_float4(a, bb, cc * ZOFF, pnew);
        } else if (lane == NS) {
            float4* dst = (float4*)(coef + (size_t)(t * 13 + 12) * 4);
            *dst = make_float4(pop, 0.f, 0.f, 0.f);
        }
        if (lane == 0) pops_out[b * S_ + t] = pop;
        p = pnew;
    }
}

// ---------- Phase D: stack scan, elementwise in (n,v) ----------
// grid (8, B), 256 threads; per-thread stack[12] in regs; coefs in LDS.
__global__ void __launch_bounds__(256) k_stack(const float* __restrict__ x,
                                               const float* __restrict__ ws,
                                               float* __restrict__ outputs,
                                               float* __restrict__ tops) {
    int b = blockIdx.y, ch = blockIdx.x;
    int tid = threadIdx.x;
    __shared__ float sc[S_ * 52];
    const float* cb = ws + WS_COEF + (size_t)b * S_ * 52;
    for (int i = tid; i < S_ * 52; i += 256) sc[i] = cb[i];
    __syncthreads();

    int v = ch * 256 + tid;
    const float* xp = x + (size_t)b * S_ * V_ + v;
    float* op = outputs + (size_t)b * S_ * V_ + v;
    float* tp = tops + (size_t)b * S_ * V_ + v;

    float st[NS];
#pragma unroll
    for (int n = 0; n < NS; n++) st[n] = ZOFF;

    for (int t = 0; t < S_; t++) {
        float xv = xp[(size_t)t * V_];
        const float* cf = &sc[t * 52];
        float top = 0.f;
#pragma unroll
        for (int n = 0; n < NS; n++) {
            float4 c4 = *(const float4*)(cf + n * 4);
            st[n] = fmaf(c4.x, st[n], fmaf(c4.y, xv, c4.z));
            top = fmaf(c4.w, st[n], top);
        }
        float pop = cf[48];
        tp[(size_t)t * V_] = top;
        op[(size_t)t * V_] = pop * top;
    }
}

extern "C" void kernel_launch(void* const* d_in, const int* in_sizes, int n_in,
                              void* d_out, int out_size, void* d_ws, size_t ws_size,
                              hipStream_t stream) {
    const float* x           = (const float*)d_in[0];
    const float* latch_init  = (const float*)d_in[1];
    const float* should_pop  = (const float*)d_in[2];
    const float* sharpen_ptr = (const float*)d_in[3];
    const float* latch_en    = (const float*)d_in[4];

    float* out = (float*)d_out;
    const size_t BSV = (size_t)B_ * S_ * V_;
    float* outputs      = out;
    float* latch_states = out + BSV;
    float* pops         = out + 2 * BSV;
    float* tops         = out + 2 * BSV + (size_t)B_ * S_;
    float* ws = (float*)d_ws;

    k_norms<<<1, 256, 0, stream>>>(latch_en, should_pop, ws);
    k_e<<<B_ * S_, 256, 0, stream>>>(x, latch_en, ws);
    k_latch<<<dim3(NCH, B_), 64, 0, stream>>>(x, latch_init, should_pop,
                                              latch_states, ws);
    k_pointer<<<B_, 64, 0, stream>>>(sharpen_ptr, ws, pops);
    k_stack<<<dim3(8, B_), 256, 0, stream>>>(x, ws, outputs, tops);
}

// Round 2
// 306.784 us; speedup vs baseline: 1.4847x; 1.4847x over previous
//
#include <hip/hip_runtime.h>
#include <math.h>

#define B_ 64
#define S_ 256
#define V_ 2048
#define NS 12
#define ZOFF 0.001f
#define EPSF 1e-8f
#define NCH 32   // v-chunks in latch phase (64 elems each)

// workspace layout (float offsets)
#define WS_NLE2 0
#define WS_NSP2 1
#define WS_E    64
#define WS_DSP  (WS_E + B_*S_)
#define WS_NL2  (WS_DSP + B_*NCH*S_)
#define WS_COEF (WS_NL2 + B_*NCH*S_)
// coef layout: [B][S][13][4] floats; n<12: (A,B,C,P), n==12: (pop,0,0,0)

__device__ __forceinline__ float wave_sum64(float v) {
#pragma unroll
    for (int m = 32; m >= 1; m >>= 1) v += __shfl_xor(v, m);
    return v;
}

// ---------- Phase A0: norms of latch_enable, should_pop ----------
__global__ void k_norms(const float* __restrict__ le, const float* __restrict__ sp,
                        float* __restrict__ ws) {
    __shared__ float red[4][2];
    int tid = threadIdx.x;
    float a = 0.f, b = 0.f;
    for (int i = tid; i < V_; i += 256) {
        float x = le[i]; a += x * x;
        float y = sp[i]; b += y * y;
    }
    a = wave_sum64(a); b = wave_sum64(b);
    int wave = tid >> 6, lane = tid & 63;
    if (lane == 0) { red[wave][0] = a; red[wave][1] = b; }
    __syncthreads();
    if (tid == 0) {
        float s0 = 0.f, s1 = 0.f;
        for (int w = 0; w < 4; w++) { s0 += red[w][0]; s1 += red[w][1]; }
        ws[WS_NLE2] = s0; ws[WS_NSP2] = s1;
    }
}

// ---------- Phase A: e[b][t] = cossim(latch_enable, x[b,t,:]) ----------
__global__ void __launch_bounds__(256) k_e(const float* __restrict__ x,
                                           const float* __restrict__ le,
                                           float* __restrict__ ws) {
    int bt = blockIdx.x;  // b*S + t
    const float4* xb = (const float4*)(x + (size_t)bt * V_);
    const float4* le4 = (const float4*)le;
    int tid = threadIdx.x;
    float dot = 0.f, nx = 0.f;
#pragma unroll
    for (int k = 0; k < 2; k++) {
        int i = tid + k * 256;
        float4 xv = xb[i], lv = le4[i];
        dot += xv.x * lv.x + xv.y * lv.y + xv.z * lv.z + xv.w * lv.w;
        nx  += xv.x * xv.x + xv.y * xv.y + xv.z * xv.z + xv.w * xv.w;
    }
    dot = wave_sum64(dot); nx = wave_sum64(nx);
    __shared__ float red[4][2];
    int wave = tid >> 6, lane = tid & 63;
    if (lane == 0) { red[wave][0] = dot; red[wave][1] = nx; }
    __syncthreads();
    if (tid == 0) {
        float d = red[0][0] + red[1][0] + red[2][0] + red[3][0];
        float n = red[0][1] + red[1][1] + red[2][1] + red[3][1];
        float nle = fmaxf(sqrtf(ws[WS_NLE2]), EPSF);
        float nxv = fmaxf(sqrtf(n), EPSF);
        ws[WS_E + bt] = d / (nle * nxv);
    }
}

// ---------- Phase B: latch scan over t, elementwise in v ----------
// grid (NCH, B), 64 threads. Depth-4 prefetch of x and e.
__global__ void __launch_bounds__(64) k_latch(const float* __restrict__ x,
                        const float* __restrict__ latch_init,
                        const float* __restrict__ sp,
                        float* __restrict__ latch_out,
                        float* __restrict__ ws) {
    int c = blockIdx.x, b = blockIdx.y;
    int lane = threadIdx.x;
    int v = c * 64 + lane;

    __shared__ float se[S_];
    for (int t = lane; t < S_; t += 64) se[t] = ws[WS_E + b * S_ + t];
    __syncthreads();

    float latch = latch_init[b * V_ + v];
    float spv = sp[v];
    const float* xb = x + (size_t)b * S_ * V_ + v;
    float* lo = latch_out + (size_t)b * S_ * V_ + v;
    float* dspp = ws + WS_DSP + (size_t)(b * NCH + c) * S_;
    float* nl2p = ws + WS_NL2 + (size_t)(b * NCH + c) * S_;

    // stats slot t holds stats of the latch USED at step t (pre-update)
    {
        float d = wave_sum64(spv * latch);
        float n = wave_sum64(latch * latch);
        if (lane == 0) { dspp[0] = d; nl2p[0] = n; }
    }

    auto step = [&](int t, float xv, float e) {
        latch = fmaf(e, xv - latch, latch);   // (1-e)*latch + e*x
        __builtin_nontemporal_store(latch, lo + (size_t)t * V_);
        if (t + 1 < S_) {
            float d = wave_sum64(spv * latch);
            float n = wave_sum64(latch * latch);
            if (lane == 0) { dspp[t + 1] = d; nl2p[t + 1] = n; }
        }
    };

    float x0 = xb[0], x1 = xb[(size_t)V_], x2 = xb[2 * (size_t)V_], x3 = xb[3 * (size_t)V_];
    float e0 = se[0], e1 = se[1], e2 = se[2], e3 = se[3];
    for (int t = 0; t < S_; t += 4) {
        float y0 = 0.f, y1 = 0.f, y2 = 0.f, y3 = 0.f;
        float f0 = 0.f, f1 = 0.f, f2 = 0.f, f3 = 0.f;
        if (t + 4 < S_) {
            y0 = xb[(size_t)(t + 4) * V_]; y1 = xb[(size_t)(t + 5) * V_];
            y2 = xb[(size_t)(t + 6) * V_]; y3 = xb[(size_t)(t + 7) * V_];
            f0 = se[t + 4]; f1 = se[t + 5]; f2 = se[t + 6]; f3 = se[t + 7];
        }
        step(t + 0, x0, e0); step(t + 1, x1, e1);
        step(t + 2, x2, e2); step(t + 3, x3, e3);
        x0 = y0; x1 = y1; x2 = y2; x3 = y3;
        e0 = f0; e1 = f1; e2 = f2; e3 = f3;
    }
}

// ---------- Phase C: pointer recurrence -> coefficients ----------
// grid (B), 64 threads. Lane n<12 owns pointer slot n.
__global__ void __launch_bounds__(64) k_pointer(const float* __restrict__ sharpen_ptr,
                          float* __restrict__ ws,
                          float* __restrict__ pops_out) {
    int b = blockIdx.x, lane = threadIdx.x;
    __shared__ float sdsp[S_], snl2[S_];
    // reduce chunk partials
    for (int t = lane; t < S_; t += 64) {
        const float* dp = ws + WS_DSP + (size_t)b * NCH * S_ + t;
        const float* np = ws + WS_NL2 + (size_t)b * NCH * S_ + t;
        float d = 0.f, n = 0.f;
#pragma unroll
        for (int c = 0; c < NCH; c++) { d += dp[c * S_]; n += np[c * S_]; }
        sdsp[t] = d; snl2[t] = n;
    }
    __syncthreads();

    float sharpen = sharpen_ptr[0];
    float inv_nsp = 1.f / fmaxf(sqrtf(ws[WS_NSP2]), EPSF);
    float p = (lane == 0) ? 1.f : 0.f;
    float* coef = ws + WS_COEF + (size_t)b * S_ * 13 * 4;

    float dsp_c = sdsp[0], nl2_c = snl2[0];
    for (int t = 0; t < S_; t++) {
        float dsp_n = 0.f, nl2_n = 0.f;
        if (t + 1 < S_) { dsp_n = sdsp[t + 1]; nl2_n = snl2[t + 1]; }
        // cossim via rsqrt (abs err ~1e-7, threshold 0.17)
        float cs = dsp_c * inv_nsp * __frsqrt_rn(fmaxf(nl2_c, EPSF * EPSF));
        float em = __expf(cs) - 1.f;
        float pop = cs > 0.f ? cs : em;
        float push = 1.f - pop;
        // softmax over 12 lanes within the 16-lane group (no max-subtract:
        // |p*sharpen| bounded ~O(10), exp safe in f32)
        float ez = (lane < NS) ? __expf(p * sharpen) : 0.f;
        float s = ez;
#pragma unroll
        for (int mm = 1; mm < 16; mm <<= 1) s += __shfl_xor(s, mm);
        float psh = ez * (1.f / s);
        int nm1 = (lane == 0) ? 11 : lane - 1;    // (n-1) mod 12
        int np1 = (lane == 11) ? 0 : lane + 1;    // (n+1) mod 12
        float push_p = __shfl(psh, nm1);
        float pop_p  = __shfl(psh, np1);
        float bb = push * push_p;
        float cc = pop * psh;
        float a  = 1.f - bb - cc;
        float pnew = fmaf(pop, pop_p, bb);
        if (lane < NS) {
            float4* dst = (float4*)(coef + (size_t)(t * 13 + lane) * 4);
            *dst = make_float4(a, bb, cc * ZOFF, pnew);
        } else if (lane == NS) {
            float4* dst = (float4*)(coef + (size_t)(t * 13 + 12) * 4);
            *dst = make_float4(pop, 0.f, 0.f, 0.f);
        }
        if (lane == 0) pops_out[b * S_ + t] = pop;
        p = pnew;
        dsp_c = dsp_n; nl2_c = nl2_n;
    }
}

// ---------- Phase D: stack scan, elementwise in (n,v) ----------
// grid (8, B), 256 threads; per-thread stack[12] in regs; coefs in LDS.
__global__ void __launch_bounds__(256) k_stack(const float* __restrict__ x,
                                               const float* __restrict__ ws,
                                               float* __restrict__ outputs,
                                               float* __restrict__ tops) {
    int b = blockIdx.y, ch = blockIdx.x;
    int tid = threadIdx.x;
    __shared__ float sc[S_ * 52];
    const float* cb = ws + WS_COEF + (size_t)b * S_ * 52;
    for (int i = tid; i < S_ * 52; i += 256) sc[i] = cb[i];
    __syncthreads();

    int v = ch * 256 + tid;
    const float* xp = x + (size_t)b * S_ * V_ + v;
    float* op = outputs + (size_t)b * S_ * V_ + v;
    float* tp = tops + (size_t)b * S_ * V_ + v;

    float st[NS];
#pragma unroll
    for (int n = 0; n < NS; n++) st[n] = ZOFF;

    auto dstep = [&](int t, float xv) {
        const float* cf = &sc[t * 52];
        float top = 0.f;
#pragma unroll
        for (int n = 0; n < NS; n++) {
            float4 c4 = *(const float4*)(cf + n * 4);
            st[n] = fmaf(c4.x, st[n], fmaf(c4.y, xv, c4.z));
            top = fmaf(c4.w, st[n], top);
        }
        float pop = cf[48];
        __builtin_nontemporal_store(top, tp + (size_t)t * V_);
        __builtin_nontemporal_store(pop * top, op + (size_t)t * V_);
    };

    float xa = __builtin_nontemporal_load(xp);
    float xb2 = __builtin_nontemporal_load(xp + (size_t)V_);
    for (int t = 0; t < S_; t += 2) {
        float na = 0.f, nb = 0.f;
        if (t + 2 < S_) {
            na = __builtin_nontemporal_load(xp + (size_t)(t + 2) * V_);
            nb = __builtin_nontemporal_load(xp + (size_t)(t + 3) * V_);
        }
        dstep(t + 0, xa);
        dstep(t + 1, xb2);
        xa = na; xb2 = nb;
    }
}

extern "C" void kernel_launch(void* const* d_in, const int* in_sizes, int n_in,
                              void* d_out, int out_size, void* d_ws, size_t ws_size,
                              hipStream_t stream) {
    const float* x           = (const float*)d_in[0];
    const float* latch_init  = (const float*)d_in[1];
    const float* should_pop  = (const float*)d_in[2];
    const float* sharpen_ptr = (const float*)d_in[3];
    const float* latch_en    = (const float*)d_in[4];

    float* out = (float*)d_out;
    const size_t BSV = (size_t)B_ * S_ * V_;
    float* outputs      = out;
    float* latch_states = out + BSV;
    float* pops         = out + 2 * BSV;
    float* tops         = out + 2 * BSV + (size_t)B_ * S_;
    float* ws = (float*)d_ws;

    k_norms<<<1, 256, 0, stream>>>(latch_en, should_pop, ws);
    k_e<<<B_ * S_, 256, 0, stream>>>(x, latch_en, ws);
    k_latch<<<dim3(NCH, B_), 64, 0, stream>>>(x, latch_init, should_pop,
                                              latch_states, ws);
    k_pointer<<<B_, 64, 0, stream>>>(sharpen_ptr, ws, pops);
    k_stack<<<dim3(8, B_), 256, 0, stream>>>(x, ws, outputs, tops);
}

// Round 3
// 268.031 us; speedup vs baseline: 1.6994x; 1.1446x over previous
//
#include <hip/hip_runtime.h>
#include <math.h>

#define B_ 64
#define S_ 256
#define V_ 2048
#define NS 12
#define ZOFF 0.001f
#define EPSF 1e-8f
#define EPS2 1e-16f
#define NCH 32   // v-chunks in latch phase (64 elems each)

// workspace layout (float offsets)
#define WS_NLE2 0
#define WS_NSP2 1
#define WS_D0   64                    // [B]
#define WS_N0   (WS_D0 + B_)          // [B]
#define WS_E    256                   // [B*S]
#define WS_R    (WS_E + B_*S_)        // [B*S]
#define WS_NX2  (WS_R + B_*S_)        // [B*S]
#define WS_H    (WS_NX2 + B_*S_)      // [B*NCH*S]
#define WS_COEF (WS_H + B_*NCH*S_)    // [B*S*13*4]
// coef layout: [B][S][13][4]; n<12: (A,B,C,P), n==12: (pop,0,0,0)

__device__ __forceinline__ float wave_sum64(float v) {
#pragma unroll
    for (int m = 32; m >= 1; m >>= 1) v += __shfl_xor(v, m);
    return v;
}

// sum across a DPP row of 16 lanes via rotate-adds (VALU-speed, no DS ops)
__device__ __forceinline__ float row16_sum(float x) {
    int t;
    t = __builtin_amdgcn_update_dpp(0, __float_as_int(x), 0x121, 0xf, 0xf, true);
    x += __int_as_float(t);  // ror:1
    t = __builtin_amdgcn_update_dpp(0, __float_as_int(x), 0x122, 0xf, 0xf, true);
    x += __int_as_float(t);  // ror:2
    t = __builtin_amdgcn_update_dpp(0, __float_as_int(x), 0x124, 0xf, 0xf, true);
    x += __int_as_float(t);  // ror:4
    t = __builtin_amdgcn_update_dpp(0, __float_as_int(x), 0x128, 0xf, 0xf, true);
    x += __int_as_float(t);  // ror:8
    return x;
}

// ---------- Phase A0: global norms + per-batch latch_init stats ----------
// block 0: ||le||^2, ||sp||^2 ; blocks 1..64: d0[b]=sp.l0, n0[b]=||l0||^2
__global__ void __launch_bounds__(256) k_norms(const float* __restrict__ le,
                        const float* __restrict__ sp,
                        const float* __restrict__ l0,
                        float* __restrict__ ws) {
    __shared__ float red[4][2];
    int tid = threadIdx.x;
    int blk = blockIdx.x;
    float a = 0.f, b = 0.f;
    if (blk == 0) {
        for (int i = tid; i < V_; i += 256) {
            float x = le[i]; a += x * x;
            float y = sp[i]; b += y * y;
        }
    } else {
        const float* lr = l0 + (size_t)(blk - 1) * V_;
        for (int i = tid; i < V_; i += 256) {
            float l = lr[i]; float s = sp[i];
            a += s * l; b += l * l;
        }
    }
    a = wave_sum64(a); b = wave_sum64(b);
    int wave = tid >> 6, lane = tid & 63;
    if (lane == 0) { red[wave][0] = a; red[wave][1] = b; }
    __syncthreads();
    if (tid == 0) {
        float s0 = 0.f, s1 = 0.f;
        for (int w = 0; w < 4; w++) { s0 += red[w][0]; s1 += red[w][1]; }
        if (blk == 0) { ws[WS_NLE2] = s0; ws[WS_NSP2] = s1; }
        else { ws[WS_D0 + blk - 1] = s0; ws[WS_N0 + blk - 1] = s1; }
    }
}

// ---------- Phase A: per (b,t): e_t, r_t = sp.x_t, nx2_t = ||x_t||^2 ----------
__global__ void __launch_bounds__(256) k_e(const float* __restrict__ x,
                                           const float* __restrict__ le,
                                           const float* __restrict__ sp,
                                           float* __restrict__ ws) {
    int bt = blockIdx.x;  // b*S + t
    const float4* xb = (const float4*)(x + (size_t)bt * V_);
    const float4* le4 = (const float4*)le;
    const float4* sp4 = (const float4*)sp;
    int tid = threadIdx.x;
    float dot = 0.f, nx = 0.f, rr = 0.f;
#pragma unroll
    for (int k = 0; k < 2; k++) {
        int i = tid + k * 256;
        float4 xv = xb[i], lv = le4[i], sv = sp4[i];
        dot += xv.x * lv.x + xv.y * lv.y + xv.z * lv.z + xv.w * lv.w;
        nx  += xv.x * xv.x + xv.y * xv.y + xv.z * xv.z + xv.w * xv.w;
        rr  += xv.x * sv.x + xv.y * sv.y + xv.z * sv.z + xv.w * sv.w;
    }
    dot = wave_sum64(dot); nx = wave_sum64(nx); rr = wave_sum64(rr);
    __shared__ float red[4][3];
    int wave = tid >> 6, lane = tid & 63;
    if (lane == 0) { red[wave][0] = dot; red[wave][1] = nx; red[wave][2] = rr; }
    __syncthreads();
    if (tid == 0) {
        float d = red[0][0] + red[1][0] + red[2][0] + red[3][0];
        float n = red[0][1] + red[1][1] + red[2][1] + red[3][1];
        float r = red[0][2] + red[1][2] + red[2][2] + red[3][2];
        float inv_nle = 1.f / fmaxf(sqrtf(ws[WS_NLE2]), EPSF);
        ws[WS_E + bt]   = d * inv_nle * __frsqrt_rn(fmaxf(n, EPS2));
        ws[WS_R + bt]   = r;
        ws[WS_NX2 + bt] = n;
    }
}

// ---------- Phase B: latch scan; only h_t = latch_t . x_t needs reducing ----------
__global__ void __launch_bounds__(64) k_latch(const float* __restrict__ x,
                        const float* __restrict__ latch_init,
                        float* __restrict__ latch_out,
                        float* __restrict__ ws) {
    int c = blockIdx.x, b = blockIdx.y;
    int lane = threadIdx.x;
    int v = c * 64 + lane;

    __shared__ float se[S_];
    for (int t = lane; t < S_; t += 64) se[t] = ws[WS_E + b * S_ + t];
    __syncthreads();

    float latch = latch_init[b * V_ + v];
    const float* xb = x + (size_t)b * S_ * V_ + v;
    float* lo = latch_out + (size_t)b * S_ * V_ + v;
    float* hpp = ws + WS_H + (size_t)(b * NCH + c) * S_;

    auto step = [&](int t, float xv, float e) {
        // h_t uses latch state ENTERING step t
        float hs = wave_sum64(latch * xv);
        if (lane == 0) hpp[t] = hs;
        latch = fmaf(e, xv - latch, latch);   // (1-e)*latch + e*x
        __builtin_nontemporal_store(latch, lo + (size_t)t * V_);
    };

    float x0 = xb[0], x1 = xb[(size_t)V_], x2 = xb[2 * (size_t)V_], x3 = xb[3 * (size_t)V_];
    float e0 = se[0], e1 = se[1], e2 = se[2], e3 = se[3];
    for (int t = 0; t < S_; t += 4) {
        float y0 = 0.f, y1 = 0.f, y2 = 0.f, y3 = 0.f;
        float f0 = 0.f, f1 = 0.f, f2 = 0.f, f3 = 0.f;
        if (t + 4 < S_) {
            y0 = xb[(size_t)(t + 4) * V_]; y1 = xb[(size_t)(t + 5) * V_];
            y2 = xb[(size_t)(t + 6) * V_]; y3 = xb[(size_t)(t + 7) * V_];
            f0 = se[t + 4]; f1 = se[t + 5]; f2 = se[t + 6]; f3 = se[t + 7];
        }
        step(t + 0, x0, e0); step(t + 1, x1, e1);
        step(t + 2, x2, e2); step(t + 3, x3, e3);
        x0 = y0; x1 = y1; x2 = y2; x3 = y3;
        e0 = f0; e1 = f1; e2 = f2; e3 = f3;
    }
}

// ---------- Phase C: scalar d/n recurrences + pointer softmax -> coefs ----------
__global__ void __launch_bounds__(64) k_pointer(const float* __restrict__ sharpen_ptr,
                          float* __restrict__ ws,
                          float* __restrict__ pops_out) {
    int b = blockIdx.x, lane = threadIdx.x;
    __shared__ float sh[S_], se_[S_], sr_[S_], snx_[S_];
    for (int t = lane; t < S_; t += 64) {
        const float* hp = ws + WS_H + (size_t)b * NCH * S_ + t;
        float h = 0.f;
#pragma unroll
        for (int c = 0; c < NCH; c++) h += hp[c * S_];
        sh[t] = h;
        se_[t]  = ws[WS_E + b * S_ + t];
        sr_[t]  = ws[WS_R + b * S_ + t];
        snx_[t] = ws[WS_NX2 + b * S_ + t];
    }
    __syncthreads();

    float sharpen = sharpen_ptr[0];
    float inv_nsp = 1.f / fmaxf(sqrtf(ws[WS_NSP2]), EPSF);
    float d = ws[WS_D0 + b];
    float n = ws[WS_N0 + b];
    float p = (lane == 0) ? 1.f : 0.f;
    float* coef = ws + WS_COEF + (size_t)b * S_ * 13 * 4;

    int nm1 = (lane == 0) ? 11 : lane - 1;    // (n-1) mod 12
    int np1 = (lane == 11) ? 0 : lane + 1;    // (n+1) mod 12

    for (int t = 0; t < S_; t++) {
        // pop from cossim(sp, latch state entering step t)
        float cs = d * inv_nsp * __frsqrt_rn(fmaxf(n, EPS2));
        float pop = cs > 0.f ? cs : __expf(cs) - 1.f;
        float push = 1.f - pop;
        // softmax over 12 lanes of the 16-lane row (DPP rotate-add sum)
        float ez = (lane < NS) ? __expf(p * sharpen) : 0.f;
        float s = row16_sum(ez);
        float psh = ez * __frcp_rn(s);
        float push_p = __shfl(psh, nm1);
        float pop_p  = __shfl(psh, np1);
        float bb = push * push_p;
        float cc = pop * psh;
        float a  = 1.f - bb - cc;
        float pnew = fmaf(pop, pop_p, bb);
        if (lane < NS) {
            float4* dst = (float4*)(coef + (size_t)(t * 13 + lane) * 4);
            *dst = make_float4(a, bb, cc * ZOFF, pnew);
        } else if (lane == NS) {
            float4* dst = (float4*)(coef + (size_t)(t * 13 + 12) * 4);
            *dst = make_float4(pop, 0.f, 0.f, 0.f);
        }
        if (lane == 0) pops_out[b * S_ + t] = pop;
        p = pnew;
        // advance d/n to state entering step t+1
        float e = se_[t], om = 1.f - e;
        d = fmaf(om, d, e * sr_[t]);
        n = om * om * n + 2.f * e * om * sh[t] + e * e * snx_[t];
    }
}

// ---------- Phase D: stack scan, elementwise in (n,v) ----------
__global__ void __launch_bounds__(256) k_stack(const float* __restrict__ x,
                                               const float* __restrict__ ws,
                                               float* __restrict__ outputs,
                                               float* __restrict__ tops) {
    int b = blockIdx.y, ch = blockIdx.x;
    int tid = threadIdx.x;
    __shared__ float sc[S_ * 52];
    const float* cb = ws + WS_COEF + (size_t)b * S_ * 52;
    for (int i = tid; i < S_ * 52; i += 256) sc[i] = cb[i];
    __syncthreads();

    int v = ch * 256 + tid;
    const float* xp = x + (size_t)b * S_ * V_ + v;
    float* op = outputs + (size_t)b * S_ * V_ + v;
    float* tp = tops + (size_t)b * S_ * V_ + v;

    float st[NS];
#pragma unroll
    for (int n = 0; n < NS; n++) st[n] = ZOFF;

    auto dstep = [&](int t, float xv) {
        const float* cf = &sc[t * 52];
        float top = 0.f;
#pragma unroll
        for (int n = 0; n < NS; n++) {
            float4 c4 = *(const float4*)(cf + n * 4);
            st[n] = fmaf(c4.x, st[n], fmaf(c4.y, xv, c4.z));
            top = fmaf(c4.w, st[n], top);
        }
        float pop = cf[48];
        __builtin_nontemporal_store(top, tp + (size_t)t * V_);
        __builtin_nontemporal_store(pop * top, op + (size_t)t * V_);
    };

    float x0 = __builtin_nontemporal_load(xp);
    float x1 = __builtin_nontemporal_load(xp + (size_t)V_);
    float x2 = __builtin_nontemporal_load(xp + 2 * (size_t)V_);
    float x3 = __builtin_nontemporal_load(xp + 3 * (size_t)V_);
    for (int t = 0; t < S_; t += 4) {
        float y0 = 0.f, y1 = 0.f, y2 = 0.f, y3 = 0.f;
        if (t + 4 < S_) {
            y0 = __builtin_nontemporal_load(xp + (size_t)(t + 4) * V_);
            y1 = __builtin_nontemporal_load(xp + (size_t)(t + 5) * V_);
            y2 = __builtin_nontemporal_load(xp + (size_t)(t + 6) * V_);
            y3 = __builtin_nontemporal_load(xp + (size_t)(t + 7) * V_);
        }
        dstep(t + 0, x0); dstep(t + 1, x1);
        dstep(t + 2, x2); dstep(t + 3, x3);
        x0 = y0; x1 = y1; x2 = y2; x3 = y3;
    }
}

extern "C" void kernel_launch(void* const* d_in, const int* in_sizes, int n_in,
                              void* d_out, int out_size, void* d_ws, size_t ws_size,
                              hipStream_t stream) {
    const float* x           = (const float*)d_in[0];
    const float* latch_init  = (const float*)d_in[1];
    const float* should_pop  = (const float*)d_in[2];
    const float* sharpen_ptr = (const float*)d_in[3];
    const float* latch_en    = (const float*)d_in[4];

    float* out = (float*)d_out;
    const size_t BSV = (size_t)B_ * S_ * V_;
    float* outputs      = out;
    float* latch_states = out + BSV;
    float* pops         = out + 2 * BSV;
    float* tops         = out + 2 * BSV + (size_t)B_ * S_;
    float* ws = (float*)d_ws;

    k_norms<<<B_ + 1, 256, 0, stream>>>(latch_en, should_pop, latch_init, ws);
    k_e<<<B_ * S_, 256, 0, stream>>>(x, latch_en, should_pop, ws);
    k_latch<<<dim3(NCH, B_), 64, 0, stream>>>(x, latch_init, latch_states, ws);
    k_pointer<<<B_, 64, 0, stream>>>(sharpen_ptr, ws, pops);
    k_stack<<<dim3(8, B_), 256, 0, stream>>>(x, ws, outputs, tops);
}